// Round 4
// baseline (1777.504 us; speedup 1.0000x reference)
//
#include <hip/hip_runtime.h>

#define NN 100000     // nodes
#define NE 1600000    // edges
#define NGR 512       // graphs
#define KF 128        // IN_F == H1
#define H2F 256
#define NGRP 16
#define NFAM 10

#define CH 128                          // nodes per chunk
#define NCHUNK ((NN + CH - 1) / CH)     // 782
#define PT 6656                         // edges per partition tile
#define NT ((NE + PT - 1) / PT)         // 241

typedef __attribute__((ext_vector_type(8))) short short8;
typedef __attribute__((ext_vector_type(4))) float floatx4;

__device__ __forceinline__ unsigned short f2bf(float f) {
  unsigned u = __float_as_uint(f);
  unsigned r = (u + 0x7fff + ((u >> 16) & 1)) >> 16;
  return (unsigned short)r;
}
__device__ __forceinline__ float2 bf2f(unsigned u) {
  float2 r;
  r.x = __uint_as_float(u << 16);
  r.y = __uint_as_float(u & 0xffff0000u);
  return r;
}

// ---------------- degree histogram (non-returning atomics) ----------------

__global__ void k_hist(const int* __restrict__ ei, int* __restrict__ cnt) {
  int e = blockIdx.x * blockDim.x + threadIdx.x;
  if (e < NE) atomicAdd(&cnt[ei[NE + e]], 1);
}

__global__ void k_dinv(const int* __restrict__ cnt, float* __restrict__ dinv) {
  int i = blockIdx.x * blockDim.x + threadIdx.x;
  if (i < NN) dinv[i] = rsqrtf((float)(cnt[i] + 1));  // +1 self loop
}

// ---------------- per-graph node ranges (batch is sorted) ----------------

__global__ void k_granges(const int* __restrict__ batch, int* __restrict__ ns) {
  int g = blockIdx.x * blockDim.x + threadIdx.x;
  if (g > NGR) return;
  if (g == NGR) { ns[NGR] = NN; return; }
  int lo = 0, hi = NN;
  while (lo < hi) { int m = (lo + hi) >> 1; if (batch[m] < g) lo = m + 1; else hi = m; }
  ns[g] = lo;
}

// ---------------- edge partition by dst chunk (dst>>7), LDS-staged ----------------

__global__ __launch_bounds__(256) void k_phist(const int* __restrict__ ei,
                                               int* __restrict__ mat) {
  __shared__ int lh[NCHUNK];
  int t0 = blockIdx.x, tid = threadIdx.x;
  for (int g = tid; g < NCHUNK; g += 256) lh[g] = 0;
  __syncthreads();
  int base = t0 * PT;
  int nv = min(PT, NE - base);
  for (int i = tid; i < nv; i += 256) atomicAdd(&lh[ei[NE + base + i] >> 7], 1);
  __syncthreads();
  for (int g = tid; g < NCHUNK; g += 256) mat[t0 * NCHUNK + g] = lh[g];
}

__global__ __launch_bounds__(256) void k_pscan(int* __restrict__ mat,
                                               int* __restrict__ cbase) {
  __shared__ int tot[NCHUNK];
  __shared__ int ssc[256];
  int tid = threadIdx.x;
  for (int g = tid; g < NCHUNK; g += 256) {
    int s = 0;
    for (int tt = 0; tt < NT; ++tt) s += mat[tt * NCHUNK + g];
    tot[g] = s;
  }
  __syncthreads();
  // exclusive scan of tot[NCHUNK] -> cbase, 4 per thread
  int v4[4]; int loc = 0;
#pragma unroll
  for (int j = 0; j < 4; ++j) {
    int idx = tid * 4 + j;
    v4[j] = (idx < NCHUNK) ? tot[idx] : 0;
    loc += v4[j];
  }
  ssc[tid] = loc;
  __syncthreads();
  for (int off = 1; off < 256; off <<= 1) {
    int val = (tid >= off) ? ssc[tid - off] : 0;
    __syncthreads();
    ssc[tid] += val;
    __syncthreads();
  }
  int excl = ssc[tid] - loc;
#pragma unroll
  for (int j = 0; j < 4; ++j) {
    int idx = tid * 4 + j;
    if (idx < NCHUNK) { tot[idx] = excl; cbase[idx] = excl; }
    excl += v4[j];
  }
  if (tid == 255) cbase[NCHUNK] = excl;  // == NE
  __syncthreads();
  // column-wise: mat[t][g] = cbase[g] + prefix over tiles
  for (int g = tid; g < NCHUNK; g += 256) {
    int acc = tot[g];
    for (int tt = 0; tt < NT; ++tt) {
      int v = mat[tt * NCHUNK + g];
      mat[tt * NCHUNK + g] = acc;
      acc += v;
    }
  }
}

__global__ __launch_bounds__(256) void k_pscatter(const int* __restrict__ ei,
                                                  const int* __restrict__ mat,
                                                  int2* __restrict__ erec) {
  __shared__ int2 stage[PT];
  __shared__ int lstart[NCHUNK];
  __shared__ int lrun[NCHUNK];
  __shared__ int loff[NCHUNK];
  __shared__ int ssc[256];
  int t0 = blockIdx.x, tid = threadIdx.x;
  for (int g = tid; g < NCHUNK; g += 256) lrun[g] = 0;
  __syncthreads();
  int base = t0 * PT;
  int nv = min(PT, NE - base);
  for (int i = tid; i < nv; i += 256) atomicAdd(&lrun[ei[NE + base + i] >> 7], 1);
  __syncthreads();
  // exclusive scan lrun -> lstart
  int v4[4]; int loc = 0;
#pragma unroll
  for (int j = 0; j < 4; ++j) {
    int idx = tid * 4 + j;
    v4[j] = (idx < NCHUNK) ? lrun[idx] : 0;
    loc += v4[j];
  }
  ssc[tid] = loc;
  __syncthreads();
  for (int off = 1; off < 256; off <<= 1) {
    int val = (tid >= off) ? ssc[tid - off] : 0;
    __syncthreads();
    ssc[tid] += val;
    __syncthreads();
  }
  int excl = ssc[tid] - loc;
#pragma unroll
  for (int j = 0; j < 4; ++j) {
    int idx = tid * 4 + j;
    if (idx < NCHUNK) lstart[idx] = excl;
    excl += v4[j];
  }
  __syncthreads();
  for (int g = tid; g < NCHUNK; g += 256) {
    lrun[g] = lstart[g];
    loff[g] = mat[t0 * NCHUNK + g];
  }
  __syncthreads();
  for (int i = tid; i < nv; i += 256) {
    int s = ei[base + i], d = ei[NE + base + i];
    int pos = atomicAdd(&lrun[d >> 7], 1);
    stage[pos] = make_int2(s, d);
  }
  __syncthreads();
  for (int j = tid; j < nv; j += 256) {
    int2 r = stage[j];
    int g = r.y >> 7;
    erec[loff[g] + (j - lstart[g])] = r;
  }
}

// ---------------- W1 pre-swizzle into MFMA B-fragment layout ----------------

__global__ void k_prepB(const float* __restrict__ W, unsigned short* __restrict__ Bp,
                        int Ncol) {
  int idx = blockIdx.x * 256 + threadIdx.x;
  int total = 128 * Ncol;
  if (idx >= total) return;
  int NCH = Ncol >> 4;
  int j = idx & 7;
  int l = (idx >> 3) & 63;
  int rest = idx >> 9;
  int nc = rest % NCH;
  int kc = rest / NCH;
  int k = kc * 32 + (l >> 4) * 8 + j;
  int nn = nc * 16 + (l & 15);
  Bp[idx] = f2bf(W[k * Ncol + nn]);
}

// ---------------- MFMA GEMM1: xw1[M,128] = x[M,128] @ W1, bf16 out ----------------

__global__ __launch_bounds__(256) void k_gemm_mfma(const float* __restrict__ A,
                                                   const unsigned short* __restrict__ Bp,
                                                   unsigned short* __restrict__ C) {
  constexpr int K = 128;
  constexpr int N = KF;
  constexpr int NCH = N / 16;
  const int wv = blockIdx.x * 4 + (threadIdx.x >> 6);
  const int row0 = wv * 16;
  if (row0 >= NN) return;  // 100000 % 16 == 0
  const int lane = threadIdx.x & 63;
  const int m = lane & 15;
  const int q = lane >> 4;

  floatx4 acc[NCH];
#pragma unroll
  for (int i = 0; i < NCH; ++i) acc[i] = (floatx4){0.f, 0.f, 0.f, 0.f};

  const int arow = row0 + m;
#pragma unroll
  for (int kc = 0; kc < 4; ++kc) {
    const float* ap = A + (size_t)arow * K + kc * 32 + q * 8;
    float4 f0 = *(const float4*)ap;
    float4 f1 = *(const float4*)(ap + 4);
    short8 af;
    af[0] = (short)f2bf(f0.x); af[1] = (short)f2bf(f0.y);
    af[2] = (short)f2bf(f0.z); af[3] = (short)f2bf(f0.w);
    af[4] = (short)f2bf(f1.x); af[5] = (short)f2bf(f1.y);
    af[6] = (short)f2bf(f1.z); af[7] = (short)f2bf(f1.w);
    const unsigned short* bp = Bp + (size_t)kc * NCH * 512;
#pragma unroll
    for (int nc = 0; nc < NCH; ++nc) {
      short8 bfr = *(const short8*)(bp + (size_t)nc * 512 + lane * 8);
      acc[nc] = __builtin_amdgcn_mfma_f32_16x16x32_bf16(af, bfr, acc[nc], 0, 0, 0);
    }
  }

#pragma unroll
  for (int nc = 0; nc < NCH; ++nc) {
#pragma unroll
    for (int r = 0; r < 4; ++r) {
      int row = row0 + q * 4 + r;
      C[(size_t)row * N + nc * 16 + m] = f2bf(acc[nc][r]);
    }
  }
}

// ---------------- conv1 aggregation per chunk: LDS f32 accumulate ----------------
// h1[n] = relu( sum_in c*xw1[src] + dinv(n)^2*xw1[n] + b1 )

__global__ __launch_bounds__(512) void k_aggc1(const unsigned* __restrict__ xww,
                                               const float* __restrict__ b1,
                                               const int* __restrict__ cbase,
                                               const int2* __restrict__ erec,
                                               const float* __restrict__ dinv,
                                               unsigned* __restrict__ h1w) {
  __shared__ float accA[CH * 64];
  __shared__ float accB[CH * 64];
  const int c = blockIdx.x;
  const int tid = threadIdx.x;
  for (int i = tid; i < CH * 64; i += 512) { accA[i] = 0.f; accB[i] = 0.f; }
  __syncthreads();
  const int t = tid & 63, w = tid >> 6;
  const int e0 = cbase[c], e1 = cbase[c + 1];
  for (int i = e0 + w * 8; i < e1; i += 64) {
    int2 rec[8]; float cf[8]; unsigned u[8]; int row[8];
#pragma unroll
    for (int j = 0; j < 8; ++j) {
      int idx = (i + j < e1) ? i + j : e0;
      rec[j] = erec[idx];
    }
#pragma unroll
    for (int j = 0; j < 8; ++j) {
      float cc = dinv[rec[j].x] * dinv[rec[j].y];
      cf[j] = (i + j < e1) ? cc : 0.f;
      row[j] = rec[j].y & (CH - 1);
    }
#pragma unroll
    for (int j = 0; j < 8; ++j) u[j] = xww[(size_t)rec[j].x * 64 + t];
#pragma unroll
    for (int j = 0; j < 8; ++j) {
      float2 f = bf2f(u[j]);
      atomicAdd(&accA[row[j] * 64 + t], cf[j] * f.x);
      atomicAdd(&accB[row[j] * 64 + t], cf[j] * f.y);
    }
  }
  __syncthreads();
  float2 bb = ((const float2*)b1)[t];
  for (int r = w; r < CH; r += 8) {
    int node = c * CH + r;
    if (node < NN) {
      unsigned u = xww[(size_t)node * 64 + t];
      float dn = dinv[node];
      float dn2 = dn * dn;
      float2 f = bf2f(u);
      float ax = accA[r * 64 + t] + dn2 * f.x + bb.x;
      float ay = accB[r * 64 + t] + dn2 * f.y + bb.y;
      ax = fmaxf(ax, 0.f);
      ay = fmaxf(ay, 0.f);
      h1w[(size_t)node * 64 + t] = (unsigned)f2bf(ax) | ((unsigned)f2bf(ay) << 16);
    }
  }
}

// ---------------- conv2 agg fused with mean-pool numerator ----------------
// praw[g] += sum over edges with dst-graph g of c*h1[src]  + sum_{n in g} dinv(n)^2*h1[n]

__global__ __launch_bounds__(512) void k_aggc2(const unsigned* __restrict__ h1w,
                                               const int* __restrict__ cbase,
                                               const int2* __restrict__ erec,
                                               const float* __restrict__ dinv,
                                               const int* __restrict__ ns,
                                               float* __restrict__ praw) {
  __shared__ float red[8][4][128];
  __shared__ int sg0;
  const int c = blockIdx.x;
  const int tid = threadIdx.x;
  if (tid == 0) {
    int lo = 0, hi = NGR - 1;
    int target = c * CH;
    while (lo < hi) {
      int m = (lo + hi + 1) >> 1;
      if (ns[m] <= target) lo = m; else hi = m - 1;
    }
    sg0 = lo;
  }
  __syncthreads();
  const int g0 = sg0;
  const int bn1 = ns[min(g0 + 1, NGR)];
  const int bn2 = ns[min(g0 + 2, NGR)];
  const int bn3 = ns[min(g0 + 3, NGR)];
  const int t = tid & 63, w = tid >> 6;
  float a0x = 0.f, a0y = 0.f, a1x = 0.f, a1y = 0.f;
  float a2x = 0.f, a2y = 0.f, a3x = 0.f, a3y = 0.f;
  const int e0 = cbase[c], e1 = cbase[c + 1];
  for (int i = e0 + w * 8; i < e1; i += 64) {
    int2 rec[8]; float cf[8]; unsigned u[8]; int sg[8];
#pragma unroll
    for (int j = 0; j < 8; ++j) {
      int idx = (i + j < e1) ? i + j : e0;
      rec[j] = erec[idx];
    }
#pragma unroll
    for (int j = 0; j < 8; ++j) {
      float cc = dinv[rec[j].x] * dinv[rec[j].y];
      cf[j] = (i + j < e1) ? cc : 0.f;
      sg[j] = (rec[j].y >= bn1) + (rec[j].y >= bn2) + (rec[j].y >= bn3);
    }
#pragma unroll
    for (int j = 0; j < 8; ++j) u[j] = h1w[(size_t)rec[j].x * 64 + t];
#pragma unroll
    for (int j = 0; j < 8; ++j) {
      float2 f = bf2f(u[j]);
      float m0 = (sg[j] == 0) ? cf[j] : 0.f;
      float m1 = (sg[j] == 1) ? cf[j] : 0.f;
      float m2 = (sg[j] == 2) ? cf[j] : 0.f;
      float m3 = (sg[j] == 3) ? cf[j] : 0.f;
      a0x = fmaf(m0, f.x, a0x); a0y = fmaf(m0, f.y, a0y);
      a1x = fmaf(m1, f.x, a1x); a1y = fmaf(m1, f.y, a1y);
      a2x = fmaf(m2, f.x, a2x); a2y = fmaf(m2, f.y, a2y);
      a3x = fmaf(m3, f.x, a3x); a3y = fmaf(m3, f.y, a3y);
    }
  }
  // self-loop terms for this chunk's nodes
  for (int r = w; r < CH; r += 8) {
    int node = c * CH + r;
    if (node < NN) {
      unsigned uu = h1w[(size_t)node * 64 + t];
      float dn = dinv[node];
      float dn2 = dn * dn;
      float2 f = bf2f(uu);
      int s = (node >= bn1) + (node >= bn2) + (node >= bn3);
      float m0 = (s == 0) ? dn2 : 0.f;
      float m1 = (s == 1) ? dn2 : 0.f;
      float m2 = (s == 2) ? dn2 : 0.f;
      float m3 = (s == 3) ? dn2 : 0.f;
      a0x = fmaf(m0, f.x, a0x); a0y = fmaf(m0, f.y, a0y);
      a1x = fmaf(m1, f.x, a1x); a1y = fmaf(m1, f.y, a1y);
      a2x = fmaf(m2, f.x, a2x); a2y = fmaf(m2, f.y, a2y);
      a3x = fmaf(m3, f.x, a3x); a3y = fmaf(m3, f.y, a3y);
    }
  }
  red[w][0][2 * t] = a0x; red[w][0][2 * t + 1] = a0y;
  red[w][1][2 * t] = a1x; red[w][1][2 * t + 1] = a1y;
  red[w][2][2 * t] = a2x; red[w][2][2 * t + 1] = a2y;
  red[w][3][2 * t] = a3x; red[w][3][2 * t + 1] = a3y;
  __syncthreads();
  int k = tid >> 7, t2 = tid & 127;
  float v = 0.f;
#pragma unroll
  for (int w2 = 0; w2 < 8; ++w2) v += red[w2][k][t2];
  int gg = g0 + k;
  if (gg < NGR) atomicAdd(&praw[gg * KF + t2], v);
}

// ---------------- heads: pooled = (praw/c) @ W2 + b2, then group/family logits ----------------

__global__ __launch_bounds__(256) void k_heads(const float* __restrict__ praw,
                                               const int* __restrict__ ns,
                                               const float* __restrict__ W2,
                                               const float* __restrict__ b2,
                                               const float* __restrict__ Wg,
                                               const float* __restrict__ bg,
                                               const float* __restrict__ Wf,
                                               const float* __restrict__ bfb,
                                               float* __restrict__ out) {
  int b = blockIdx.x;
  int t = threadIdx.x;  // 256
  __shared__ float pr[KF];
  __shared__ float p[H2F];
  if (t < KF) {
    float cg = fmaxf((float)(ns[b + 1] - ns[b]), 1.f);
    pr[t] = praw[b * KF + t] / cg;
  }
  __syncthreads();
  float acc = b2[t];
#pragma unroll 8
  for (int d = 0; d < KF; ++d) acc = fmaf(pr[d], W2[d * H2F + t], acc);
  p[t] = acc;
  __syncthreads();
  if (t < NGRP) {
    float a = bg[t];
    for (int d = 0; d < H2F; ++d) a = fmaf(p[d], Wg[d * NGRP + t], a);
    out[b * NGRP + t] = a;
  } else if (t >= 64 && t < 64 + NGRP * NFAM) {
    int u = t - 64;
    int g = u / NFAM;
    int ff = u % NFAM;
    float a = bfb[g * NFAM + ff];
    for (int d = 0; d < H2F; ++d) a = fmaf(p[d], Wf[(g * H2F + d) * NFAM + ff], a);
    out[NGR * NGRP + (size_t)g * NGR * NFAM + b * NFAM + ff] = a;
  }
}

// ---------------- launch ----------------

extern "C" void kernel_launch(void* const* d_in, const int* in_sizes, int n_in,
                              void* d_out, int out_size, void* d_ws, size_t ws_size,
                              hipStream_t stream) {
  const float* x    = (const float*)d_in[0];
  const int*   ei   = (const int*)d_in[1];
  const int*   batch= (const int*)d_in[2];
  const float* W1   = (const float*)d_in[3];
  const float* b1   = (const float*)d_in[4];
  const float* W2   = (const float*)d_in[5];
  const float* b2   = (const float*)d_in[6];
  const float* Wg   = (const float*)d_in[7];
  const float* bg   = (const float*)d_in[8];
  const float* Wf   = (const float*)d_in[9];
  const float* bfb  = (const float*)d_in[10];
  float* out = (float*)d_out;

  char* w = (char*)d_ws;
  auto take = [&](size_t bytes) {
    char* p = w;
    w += (bytes + 255) & ~(size_t)255;
    return (void*)p;
  };
  // cnt and praw adjacent -> single memset covers both
  int*   cnt   = (int*)take((size_t)NN * 4);        // rounds to 400128
  float* praw  = (float*)take((size_t)NGR * KF * 4);  // 262144
  size_t zeroBytes = ((size_t)NN * 4 + 255 & ~(size_t)255) + (size_t)NGR * KF * 4;
  float* dinv  = (float*)take((size_t)NN * 4);
  int*   ns    = (int*)take((size_t)(NGR + 1) * 4);
  int*   mat   = (int*)take((size_t)NT * NCHUNK * 4);
  int*   cbase = (int*)take((size_t)(NCHUNK + 1) * 4);
  int2*  erec  = (int2*)take((size_t)NT * PT * 8);
  unsigned short* Bp1 = (unsigned short*)take((size_t)KF * KF * 2);
  unsigned* xw1 = (unsigned*)take((size_t)NN * KF * 2);
  unsigned* h1  = (unsigned*)take((size_t)NN * KF * 2);

  hipMemsetAsync(cnt, 0, zeroBytes, stream);
  k_hist<<<(NE + 255) / 256, 256, 0, stream>>>(ei, cnt);
  k_dinv<<<(NN + 255) / 256, 256, 0, stream>>>(cnt, dinv);
  k_granges<<<3, 256, 0, stream>>>(batch, ns);

  k_phist<<<NT, 256, 0, stream>>>(ei, mat);
  k_pscan<<<1, 256, 0, stream>>>(mat, cbase);
  k_pscatter<<<NT, 256, 0, stream>>>(ei, mat, erec);

  k_prepB<<<(KF * KF + 255) / 256, 256, 0, stream>>>(W1, Bp1, KF);
  k_gemm_mfma<<<1563, 256, 0, stream>>>(x, Bp1, (unsigned short*)xw1);

  k_aggc1<<<NCHUNK, 512, 0, stream>>>(xw1, b1, cbase, erec, dinv, h1);
  k_aggc2<<<NCHUNK, 512, 0, stream>>>(h1, cbase, erec, dinv, ns, praw);

  k_heads<<<NGR, 256, 0, stream>>>(praw, ns, W2, b2, Wg, bg, Wf, bfb, out);
}

// Round 5
// 401.633 us; speedup vs baseline: 4.4257x; 4.4257x over previous
//
#include <hip/hip_runtime.h>

#define NN 100000     // nodes
#define NE 1600000    // edges
#define NGR 512       // graphs
#define KF 128        // IN_F == H1
#define H2F 256
#define NGRP 16
#define NFAM 10

#define CH 128                          // nodes per chunk
#define NCHUNK ((NN + CH - 1) / CH)     // 782
#define PT 6656                         // edges per partition tile
#define NT ((NE + PT - 1) / PT)         // 241

typedef __attribute__((ext_vector_type(8))) short short8;
typedef __attribute__((ext_vector_type(4))) float floatx4;

__device__ __forceinline__ unsigned short f2bf(float f) {
  unsigned u = __float_as_uint(f);
  unsigned r = (u + 0x7fff + ((u >> 16) & 1)) >> 16;
  return (unsigned short)r;
}
__device__ __forceinline__ float2 bf2f(unsigned u) {
  float2 r;
  r.x = __uint_as_float(u << 16);
  r.y = __uint_as_float(u & 0xffff0000u);
  return r;
}

// ---------------- edge partition by dst chunk (dst>>7), LDS-staged ----------------
// (verified in R4: low cost, no scatter write amplification)

__global__ __launch_bounds__(256) void k_phist(const int* __restrict__ ei,
                                               int* __restrict__ mat) {
  __shared__ int lh[NCHUNK];
  int t0 = blockIdx.x, tid = threadIdx.x;
  for (int g = tid; g < NCHUNK; g += 256) lh[g] = 0;
  __syncthreads();
  int base = t0 * PT;
  int nv = min(PT, NE - base);
  for (int i = tid; i < nv; i += 256) atomicAdd(&lh[ei[NE + base + i] >> 7], 1);
  __syncthreads();
  for (int g = tid; g < NCHUNK; g += 256) mat[t0 * NCHUNK + g] = lh[g];
}

__global__ __launch_bounds__(256) void k_pscan(int* __restrict__ mat,
                                               int* __restrict__ cbase) {
  __shared__ int tot[NCHUNK];
  __shared__ int ssc[256];
  int tid = threadIdx.x;
  for (int g = tid; g < NCHUNK; g += 256) {
    int s = 0;
    for (int tt = 0; tt < NT; ++tt) s += mat[tt * NCHUNK + g];
    tot[g] = s;
  }
  __syncthreads();
  int v4[4]; int loc = 0;
#pragma unroll
  for (int j = 0; j < 4; ++j) {
    int idx = tid * 4 + j;
    v4[j] = (idx < NCHUNK) ? tot[idx] : 0;
    loc += v4[j];
  }
  ssc[tid] = loc;
  __syncthreads();
  for (int off = 1; off < 256; off <<= 1) {
    int val = (tid >= off) ? ssc[tid - off] : 0;
    __syncthreads();
    ssc[tid] += val;
    __syncthreads();
  }
  int excl = ssc[tid] - loc;
#pragma unroll
  for (int j = 0; j < 4; ++j) {
    int idx = tid * 4 + j;
    if (idx < NCHUNK) { tot[idx] = excl; cbase[idx] = excl; }
    excl += v4[j];
  }
  if (tid == 255) cbase[NCHUNK] = excl;  // == NE
  __syncthreads();
  for (int g = tid; g < NCHUNK; g += 256) {
    int acc = tot[g];
    for (int tt = 0; tt < NT; ++tt) {
      int v = mat[tt * NCHUNK + g];
      mat[tt * NCHUNK + g] = acc;
      acc += v;
    }
  }
}

__global__ __launch_bounds__(256) void k_pscatter(const int* __restrict__ ei,
                                                  const int* __restrict__ mat,
                                                  int2* __restrict__ erec) {
  __shared__ int2 stage[PT];
  __shared__ int lstart[NCHUNK];
  __shared__ int lrun[NCHUNK];
  __shared__ int loff[NCHUNK];
  __shared__ int ssc[256];
  int t0 = blockIdx.x, tid = threadIdx.x;
  for (int g = tid; g < NCHUNK; g += 256) lrun[g] = 0;
  __syncthreads();
  int base = t0 * PT;
  int nv = min(PT, NE - base);
  for (int i = tid; i < nv; i += 256) atomicAdd(&lrun[ei[NE + base + i] >> 7], 1);
  __syncthreads();
  int v4[4]; int loc = 0;
#pragma unroll
  for (int j = 0; j < 4; ++j) {
    int idx = tid * 4 + j;
    v4[j] = (idx < NCHUNK) ? lrun[idx] : 0;
    loc += v4[j];
  }
  ssc[tid] = loc;
  __syncthreads();
  for (int off = 1; off < 256; off <<= 1) {
    int val = (tid >= off) ? ssc[tid - off] : 0;
    __syncthreads();
    ssc[tid] += val;
    __syncthreads();
  }
  int excl = ssc[tid] - loc;
#pragma unroll
  for (int j = 0; j < 4; ++j) {
    int idx = tid * 4 + j;
    if (idx < NCHUNK) lstart[idx] = excl;
    excl += v4[j];
  }
  __syncthreads();
  for (int g = tid; g < NCHUNK; g += 256) {
    lrun[g] = lstart[g];
    loff[g] = mat[t0 * NCHUNK + g];
  }
  __syncthreads();
  for (int i = tid; i < nv; i += 256) {
    int s = ei[base + i], d = ei[NE + base + i];
    int pos = atomicAdd(&lrun[d >> 7], 1);
    stage[pos] = make_int2(s, d);
  }
  __syncthreads();
  for (int j = tid; j < nv; j += 256) {
    int2 r = stage[j];
    int g = r.y >> 7;
    erec[loff[g] + (j - lstart[g])] = r;
  }
}

// ---------------- per-chunk counting sort into per-node runs ----------------
// writes esrc (sorted by dst) + rowptr; each block writes ONLY its own
// contiguous [cbase[c], cbase[c+1]) range -> no cross-XCD write amplification.

__global__ __launch_bounds__(256) void k_sort(const int2* __restrict__ erec,
                                              const int* __restrict__ cbase,
                                              int* __restrict__ esrc,
                                              int* __restrict__ rowptr) {
  __shared__ int hist[CH];
  __shared__ int lrun[CH];
  __shared__ int sc[256];
  const int c = blockIdx.x, tid = threadIdx.x;
  const int e0 = cbase[c], e1 = cbase[c + 1];
  const int nv = e1 - e0;
  if (tid < CH) hist[tid] = 0;
  __syncthreads();
  for (int i = tid; i < nv; i += 256) atomicAdd(&hist[erec[e0 + i].y & (CH - 1)], 1);
  __syncthreads();
  int v = (tid < CH) ? hist[tid] : 0;
  sc[tid] = v;
  __syncthreads();
  for (int off = 1; off < 256; off <<= 1) {
    int val = (tid >= off) ? sc[tid - off] : 0;
    __syncthreads();
    sc[tid] += val;
    __syncthreads();
  }
  int excl = sc[tid] - v;  // exclusive scan for tid < CH
  if (tid < CH) lrun[tid] = excl;
  int node = c * CH + tid;
  if (tid <= CH && node <= NN) rowptr[node] = e0 + ((tid < CH) ? excl : nv);
  __syncthreads();
  for (int i = tid; i < nv; i += 256) {
    int2 r = erec[e0 + i];
    int pos = atomicAdd(&lrun[r.y & (CH - 1)], 1);
    esrc[e0 + pos] = r.x;
  }
}

__global__ void k_dinv(const int* __restrict__ rowptr, float* __restrict__ dinv) {
  int i = blockIdx.x * blockDim.x + threadIdx.x;
  if (i < NN) dinv[i] = rsqrtf((float)(rowptr[i + 1] - rowptr[i] + 1));  // +1 self loop
}

// ---------------- W1 pre-swizzle into MFMA B-fragment layout ----------------

__global__ void k_prepB(const float* __restrict__ W, unsigned short* __restrict__ Bp,
                        int Ncol) {
  int idx = blockIdx.x * 256 + threadIdx.x;
  int total = 128 * Ncol;
  if (idx >= total) return;
  int NCH = Ncol >> 4;
  int j = idx & 7;
  int l = (idx >> 3) & 63;
  int rest = idx >> 9;
  int nc = rest % NCH;
  int kc = rest / NCH;
  int k = kc * 32 + (l >> 4) * 8 + j;
  int nn = nc * 16 + (l & 15);
  Bp[idx] = f2bf(W[k * Ncol + nn]);
}

// ---------------- MFMA GEMM1: xw1[M,128] = x[M,128] @ W1, bf16 out ----------------

__global__ __launch_bounds__(256) void k_gemm_mfma(const float* __restrict__ A,
                                                   const unsigned short* __restrict__ Bp,
                                                   unsigned short* __restrict__ C) {
  constexpr int K = 128;
  constexpr int N = KF;
  constexpr int NCH = N / 16;
  const int wv = blockIdx.x * 4 + (threadIdx.x >> 6);
  const int row0 = wv * 16;
  if (row0 >= NN) return;  // 100000 % 16 == 0
  const int lane = threadIdx.x & 63;
  const int m = lane & 15;
  const int q = lane >> 4;

  floatx4 acc[NCH];
#pragma unroll
  for (int i = 0; i < NCH; ++i) acc[i] = (floatx4){0.f, 0.f, 0.f, 0.f};

  const int arow = row0 + m;
#pragma unroll
  for (int kc = 0; kc < 4; ++kc) {
    const float* ap = A + (size_t)arow * K + kc * 32 + q * 8;
    float4 f0 = *(const float4*)ap;
    float4 f1 = *(const float4*)(ap + 4);
    short8 af;
    af[0] = (short)f2bf(f0.x); af[1] = (short)f2bf(f0.y);
    af[2] = (short)f2bf(f0.z); af[3] = (short)f2bf(f0.w);
    af[4] = (short)f2bf(f1.x); af[5] = (short)f2bf(f1.y);
    af[6] = (short)f2bf(f1.z); af[7] = (short)f2bf(f1.w);
    const unsigned short* bp = Bp + (size_t)kc * NCH * 512;
#pragma unroll
    for (int nc = 0; nc < NCH; ++nc) {
      short8 bfr = *(const short8*)(bp + (size_t)nc * 512 + lane * 8);
      acc[nc] = __builtin_amdgcn_mfma_f32_16x16x32_bf16(af, bfr, acc[nc], 0, 0, 0);
    }
  }

#pragma unroll
  for (int nc = 0; nc < NCH; ++nc) {
#pragma unroll
    for (int r = 0; r < 4; ++r) {
      int row = row0 + q * 4 + r;
      C[(size_t)row * N + nc * 16 + m] = f2bf(acc[nc][r]);
    }
  }
}

// ---------------- aggregation, F=128: one wave per node, 8-edge unrolled ----------------
// out[n] = sum_in dinv[src]*dinv[n]*xw[src] + dinv(n)^2*xw[n]  (+bias) (relu)

template <bool RELU, bool BIAS>
__global__ __launch_bounds__(128) void k_agg(const unsigned* __restrict__ p,
                                             const float* __restrict__ bias,
                                             const int* __restrict__ rowptr,
                                             const int* __restrict__ esrc,
                                             const float* __restrict__ dinv,
                                             unsigned* __restrict__ out) {
  const int n = blockIdx.x * 2 + (threadIdx.x >> 6);
  const int t = threadIdx.x & 63;

  const float dn = dinv[n];
  const float dn2 = dn * dn;
  float2 f = bf2f(p[(size_t)n * 64 + t]);
  float ax = f.x * dn2, ay = f.y * dn2;

  const int r0 = rowptr[n];
  const int r1 = rowptr[n + 1];
  int i = r0;
  for (; i + 8 <= r1; i += 8) {
    int s0 = esrc[i], s1 = esrc[i + 1], s2 = esrc[i + 2], s3 = esrc[i + 3];
    int s4 = esrc[i + 4], s5 = esrc[i + 5], s6 = esrc[i + 6], s7 = esrc[i + 7];
    float c0 = dinv[s0] * dn, c1 = dinv[s1] * dn, c2 = dinv[s2] * dn, c3 = dinv[s3] * dn;
    float c4 = dinv[s4] * dn, c5 = dinv[s5] * dn, c6 = dinv[s6] * dn, c7 = dinv[s7] * dn;
    unsigned u0 = p[(size_t)s0 * 64 + t];
    unsigned u1 = p[(size_t)s1 * 64 + t];
    unsigned u2 = p[(size_t)s2 * 64 + t];
    unsigned u3 = p[(size_t)s3 * 64 + t];
    unsigned u4 = p[(size_t)s4 * 64 + t];
    unsigned u5 = p[(size_t)s5 * 64 + t];
    unsigned u6 = p[(size_t)s6 * 64 + t];
    unsigned u7 = p[(size_t)s7 * 64 + t];
    f = bf2f(u0); ax = fmaf(c0, f.x, ax); ay = fmaf(c0, f.y, ay);
    f = bf2f(u1); ax = fmaf(c1, f.x, ax); ay = fmaf(c1, f.y, ay);
    f = bf2f(u2); ax = fmaf(c2, f.x, ax); ay = fmaf(c2, f.y, ay);
    f = bf2f(u3); ax = fmaf(c3, f.x, ax); ay = fmaf(c3, f.y, ay);
    f = bf2f(u4); ax = fmaf(c4, f.x, ax); ay = fmaf(c4, f.y, ay);
    f = bf2f(u5); ax = fmaf(c5, f.x, ax); ay = fmaf(c5, f.y, ay);
    f = bf2f(u6); ax = fmaf(c6, f.x, ax); ay = fmaf(c6, f.y, ay);
    f = bf2f(u7); ax = fmaf(c7, f.x, ax); ay = fmaf(c7, f.y, ay);
  }
  for (; i + 4 <= r1; i += 4) {
    int s0 = esrc[i], s1 = esrc[i + 1], s2 = esrc[i + 2], s3 = esrc[i + 3];
    float c0 = dinv[s0] * dn, c1 = dinv[s1] * dn, c2 = dinv[s2] * dn, c3 = dinv[s3] * dn;
    unsigned u0 = p[(size_t)s0 * 64 + t];
    unsigned u1 = p[(size_t)s1 * 64 + t];
    unsigned u2 = p[(size_t)s2 * 64 + t];
    unsigned u3 = p[(size_t)s3 * 64 + t];
    f = bf2f(u0); ax = fmaf(c0, f.x, ax); ay = fmaf(c0, f.y, ay);
    f = bf2f(u1); ax = fmaf(c1, f.x, ax); ay = fmaf(c1, f.y, ay);
    f = bf2f(u2); ax = fmaf(c2, f.x, ax); ay = fmaf(c2, f.y, ay);
    f = bf2f(u3); ax = fmaf(c3, f.x, ax); ay = fmaf(c3, f.y, ay);
  }
  for (; i < r1; ++i) {
    int s = esrc[i];
    float c = dinv[s] * dn;
    f = bf2f(p[(size_t)s * 64 + t]);
    ax = fmaf(c, f.x, ax); ay = fmaf(c, f.y, ay);
  }

  if (BIAS) {
    float2 bb = ((const float2*)bias)[t];
    ax += bb.x; ay += bb.y;
  }
  if (RELU) { ax = fmaxf(ax, 0.f); ay = fmaxf(ay, 0.f); }
  out[(size_t)n * 64 + t] = (unsigned)f2bf(ax) | ((unsigned)f2bf(ay) << 16);
}

// ---------------- mean pool over sorted batch (F=128, bf16 in, f32 out) ----------------

__global__ __launch_bounds__(256) void k_pool(const unsigned* __restrict__ p,
                                              const int* __restrict__ batch,
                                              float* __restrict__ pooled_raw) {
  int g = blockIdx.x;
  int t = threadIdx.x & 63;   // feature uint (2 bf16)
  int wv = threadIdx.x >> 6;  // 4 waves split the node range
  int lo = 0, hi = NN;
  while (lo < hi) { int mid = (lo + hi) >> 1; if (batch[mid] < g) lo = mid + 1; else hi = mid; }
  int start = lo;
  hi = NN;
  while (lo < hi) { int mid = (lo + hi) >> 1; if (batch[mid] < g + 1) lo = mid + 1; else hi = mid; }
  int end = lo;

  float sx = 0.f, sy = 0.f;
  int n = start + wv;
  for (; n + 12 < end; n += 16) {
    unsigned u0 = p[(size_t)n * 64 + t];
    unsigned u1 = p[(size_t)(n + 4) * 64 + t];
    unsigned u2 = p[(size_t)(n + 8) * 64 + t];
    unsigned u3 = p[(size_t)(n + 12) * 64 + t];
    float2 f0 = bf2f(u0), f1 = bf2f(u1), f2 = bf2f(u2), f3 = bf2f(u3);
    sx += (f0.x + f1.x) + (f2.x + f3.x);
    sy += (f0.y + f1.y) + (f2.y + f3.y);
  }
  for (; n < end; n += 4) {
    float2 f = bf2f(p[(size_t)n * 64 + t]);
    sx += f.x; sy += f.y;
  }

  __shared__ float sh[4][128];
  sh[wv][2 * t] = sx;
  sh[wv][2 * t + 1] = sy;
  __syncthreads();
  if (wv == 0) {
    float vx = sh[0][2 * t] + sh[1][2 * t] + sh[2][2 * t] + sh[3][2 * t];
    float vy = sh[0][2 * t + 1] + sh[1][2 * t + 1] + sh[2][2 * t + 1] + sh[3][2 * t + 1];
    float c = fmaxf((float)(end - start), 1.f);
    pooled_raw[g * KF + 2 * t] = vx / c;
    pooled_raw[g * KF + 2 * t + 1] = vy / c;
  }
}

// ---------------- fused mini-GEMM (pooled = praw @ W2 + b2) + heads ----------------

__global__ __launch_bounds__(256) void k_heads(const float* __restrict__ praw,
                                               const float* __restrict__ W2,
                                               const float* __restrict__ b2,
                                               const float* __restrict__ Wg,
                                               const float* __restrict__ bg,
                                               const float* __restrict__ Wf,
                                               const float* __restrict__ bfb,
                                               float* __restrict__ out) {
  int b = blockIdx.x;
  int t = threadIdx.x;  // 256
  __shared__ float pr[KF];
  __shared__ float p[H2F];
  if (t < KF) pr[t] = praw[b * KF + t];
  __syncthreads();
  float acc = b2[t];
#pragma unroll 8
  for (int d = 0; d < KF; ++d) acc = fmaf(pr[d], W2[d * H2F + t], acc);
  p[t] = acc;
  __syncthreads();
  if (t < NGRP) {
    float a = bg[t];
    for (int d = 0; d < H2F; ++d) a = fmaf(p[d], Wg[d * NGRP + t], a);
    out[b * NGRP + t] = a;
  } else if (t >= 64 && t < 64 + NGRP * NFAM) {
    int u = t - 64;
    int g = u / NFAM;
    int ff = u % NFAM;
    float a = bfb[g * NFAM + ff];
    for (int d = 0; d < H2F; ++d) a = fmaf(p[d], Wf[(g * H2F + d) * NFAM + ff], a);
    out[NGR * NGRP + (size_t)g * NGR * NFAM + b * NFAM + ff] = a;
  }
}

// ---------------- launch ----------------

extern "C" void kernel_launch(void* const* d_in, const int* in_sizes, int n_in,
                              void* d_out, int out_size, void* d_ws, size_t ws_size,
                              hipStream_t stream) {
  const float* x    = (const float*)d_in[0];
  const int*   ei   = (const int*)d_in[1];
  const int*   batch= (const int*)d_in[2];
  const float* W1   = (const float*)d_in[3];
  const float* b1   = (const float*)d_in[4];
  const float* W2   = (const float*)d_in[5];
  const float* b2   = (const float*)d_in[6];
  const float* Wg   = (const float*)d_in[7];
  const float* bg   = (const float*)d_in[8];
  const float* Wf   = (const float*)d_in[9];
  const float* bfb  = (const float*)d_in[10];
  float* out = (float*)d_out;

  char* w = (char*)d_ws;
  auto take = [&](size_t bytes) {
    char* p = w;
    w += (bytes + 255) & ~(size_t)255;
    return (void*)p;
  };
  int*   mat   = (int*)take((size_t)NT * NCHUNK * 4);
  int*   cbase = (int*)take((size_t)(NCHUNK + 1) * 4);
  int2*  erec  = (int2*)take((size_t)NT * PT * 8);
  int*   esrc  = (int*)take((size_t)NE * 4);
  int*   rowptr= (int*)take((size_t)(NN + 1) * 4);
  float* dinv  = (float*)take((size_t)NN * 4);
  float* praw  = (float*)take((size_t)NGR * KF * 4);
  unsigned short* Bp1 = (unsigned short*)take((size_t)KF * KF * 2);
  unsigned* xw1 = (unsigned*)take((size_t)NN * KF * 2);
  unsigned* h1  = (unsigned*)take((size_t)NN * KF * 2);
  unsigned* agg2= (unsigned*)take((size_t)NN * KF * 2);

  k_phist<<<NT, 256, 0, stream>>>(ei, mat);
  k_pscan<<<1, 256, 0, stream>>>(mat, cbase);
  k_pscatter<<<NT, 256, 0, stream>>>(ei, mat, erec);
  k_sort<<<NCHUNK, 256, 0, stream>>>(erec, cbase, esrc, rowptr);
  k_dinv<<<(NN + 255) / 256, 256, 0, stream>>>(rowptr, dinv);

  k_prepB<<<(KF * KF + 255) / 256, 256, 0, stream>>>(W1, Bp1, KF);
  k_gemm_mfma<<<1563, 256, 0, stream>>>(x, Bp1, (unsigned short*)xw1);

  k_agg<true, true><<<NN / 2, 128, 0, stream>>>(xw1, b1, rowptr, esrc, dinv, h1);
  k_agg<false, false><<<NN / 2, 128, 0, stream>>>(h1, nullptr, rowptr, esrc, dinv, agg2);

  k_pool<<<NGR, 256, 0, stream>>>(agg2, batch, praw);
  k_heads<<<NGR, 256, 0, stream>>>(praw, W2, b2, Wg, bg, Wf, bfb, out);
}

// Round 6
// 344.850 us; speedup vs baseline: 5.1544x; 1.1647x over previous
//
#include <hip/hip_runtime.h>

#define NN 100000     // nodes
#define NE 1600000    // edges
#define NGR 512       // graphs
#define KF 128        // IN_F == H1
#define H2F 256
#define NGRP 16
#define NFAM 10

#define CH 128                          // nodes per chunk
#define NCHUNK ((NN + CH - 1) / CH)     // 782
#define PT 6656                         // edges per partition tile
#define NT ((NE + PT - 1) / PT)         // 241

typedef __attribute__((ext_vector_type(8))) short short8;
typedef __attribute__((ext_vector_type(4))) float floatx4;

__device__ __forceinline__ unsigned short f2bf(float f) {
  unsigned u = __float_as_uint(f);
  unsigned r = (u + 0x7fff + ((u >> 16) & 1)) >> 16;
  return (unsigned short)r;
}
__device__ __forceinline__ float2 bf2f(unsigned u) {
  float2 r;
  r.x = __uint_as_float(u << 16);
  r.y = __uint_as_float(u & 0xffff0000u);
  return r;
}

// ---------------- edge partition by dst chunk (dst>>7), LDS-staged ----------------

__global__ __launch_bounds__(256) void k_phist(const int* __restrict__ ei,
                                               int* __restrict__ mat) {
  __shared__ int lh[NCHUNK];
  int t0 = blockIdx.x, tid = threadIdx.x;
  for (int g = tid; g < NCHUNK; g += 256) lh[g] = 0;
  __syncthreads();
  int base = t0 * PT;
  int nv = min(PT, NE - base);
  for (int i = tid; i < nv; i += 256) atomicAdd(&lh[ei[NE + base + i] >> 7], 1);
  __syncthreads();
  for (int g = tid; g < NCHUNK; g += 256) mat[t0 * NCHUNK + g] = lh[g];
}

// column sums of mat -> tot[NCHUNK]; one wave per column
__global__ __launch_bounds__(256) void k_colsum(const int* __restrict__ mat,
                                                int* __restrict__ tot) {
  int g = blockIdx.x * 4 + (threadIdx.x >> 6);
  if (g >= NCHUNK) return;
  int lane = threadIdx.x & 63;
  int s = 0;
  for (int t = lane; t < NT; t += 64) s += mat[t * NCHUNK + g];
#pragma unroll
  for (int off = 32; off > 0; off >>= 1) s += __shfl_down(s, off);
  if (lane == 0) tot[g] = s;
}

// exclusive scan of tot[NCHUNK] -> cbase (single small block)
__global__ __launch_bounds__(256) void k_scantot(const int* __restrict__ tot,
                                                 int* __restrict__ cbase) {
  __shared__ int ssc[256];
  int tid = threadIdx.x;
  int v4[4]; int loc = 0;
#pragma unroll
  for (int j = 0; j < 4; ++j) {
    int idx = tid * 4 + j;
    v4[j] = (idx < NCHUNK) ? tot[idx] : 0;
    loc += v4[j];
  }
  ssc[tid] = loc;
  __syncthreads();
  for (int off = 1; off < 256; off <<= 1) {
    int val = (tid >= off) ? ssc[tid - off] : 0;
    __syncthreads();
    ssc[tid] += val;
    __syncthreads();
  }
  int excl = ssc[tid] - loc;
#pragma unroll
  for (int j = 0; j < 4; ++j) {
    int idx = tid * 4 + j;
    if (idx < NCHUNK) cbase[idx] = excl;
    excl += v4[j];
  }
  if (tid == 255) cbase[NCHUNK] = excl;  // == NE
}

// per-column prefix over tiles: mat[t][g] = cbase[g] + sum_{t'<t} count; one wave/column
__global__ __launch_bounds__(256) void k_colfix(int* __restrict__ mat,
                                                const int* __restrict__ cbase) {
  int g = blockIdx.x * 4 + (threadIdx.x >> 6);
  if (g >= NCHUNK) return;
  int lane = threadIdx.x & 63;
  int v[4]; int loc = 0;
#pragma unroll
  for (int j = 0; j < 4; ++j) {
    int t = lane * 4 + j;
    v[j] = (t < NT) ? mat[t * NCHUNK + g] : 0;
    loc += v[j];
  }
  int incl = loc;
#pragma unroll
  for (int off = 1; off < 64; off <<= 1) {
    int o = __shfl_up(incl, off);
    if (lane >= off) incl += o;
  }
  int excl = incl - loc + cbase[g];
#pragma unroll
  for (int j = 0; j < 4; ++j) {
    int t = lane * 4 + j;
    if (t < NT) mat[t * NCHUNK + g] = excl;
    excl += v[j];
  }
}

__global__ __launch_bounds__(256) void k_pscatter(const int* __restrict__ ei,
                                                  const int* __restrict__ mat,
                                                  int2* __restrict__ erec) {
  __shared__ int2 stage[PT];
  __shared__ int lstart[NCHUNK];
  __shared__ int lrun[NCHUNK];
  __shared__ int loff[NCHUNK];
  __shared__ int ssc[256];
  int t0 = blockIdx.x, tid = threadIdx.x;
  for (int g = tid; g < NCHUNK; g += 256) lrun[g] = 0;
  __syncthreads();
  int base = t0 * PT;
  int nv = min(PT, NE - base);
  for (int i = tid; i < nv; i += 256) atomicAdd(&lrun[ei[NE + base + i] >> 7], 1);
  __syncthreads();
  int v4[4]; int loc = 0;
#pragma unroll
  for (int j = 0; j < 4; ++j) {
    int idx = tid * 4 + j;
    v4[j] = (idx < NCHUNK) ? lrun[idx] : 0;
    loc += v4[j];
  }
  ssc[tid] = loc;
  __syncthreads();
  for (int off = 1; off < 256; off <<= 1) {
    int val = (tid >= off) ? ssc[tid - off] : 0;
    __syncthreads();
    ssc[tid] += val;
    __syncthreads();
  }
  int excl = ssc[tid] - loc;
#pragma unroll
  for (int j = 0; j < 4; ++j) {
    int idx = tid * 4 + j;
    if (idx < NCHUNK) lstart[idx] = excl;
    excl += v4[j];
  }
  __syncthreads();
  for (int g = tid; g < NCHUNK; g += 256) {
    lrun[g] = lstart[g];
    loff[g] = mat[t0 * NCHUNK + g];
  }
  __syncthreads();
  for (int i = tid; i < nv; i += 256) {
    int s = ei[base + i], d = ei[NE + base + i];
    int pos = atomicAdd(&lrun[d >> 7], 1);
    stage[pos] = make_int2(s, d);
  }
  __syncthreads();
  for (int j = tid; j < nv; j += 256) {
    int2 r = stage[j];
    int g = r.y >> 7;
    erec[loff[g] + (j - lstart[g])] = r;
  }
}

// ---------------- per-chunk counting sort into per-node runs (+dinv fused) ----------------

__global__ __launch_bounds__(256) void k_sort(const int2* __restrict__ erec,
                                              const int* __restrict__ cbase,
                                              int* __restrict__ esrc,
                                              int* __restrict__ rowptr,
                                              float* __restrict__ dinv) {
  __shared__ int hist[CH];
  __shared__ int lrun[CH];
  __shared__ int sc[256];
  const int c = blockIdx.x, tid = threadIdx.x;
  const int e0 = cbase[c], e1 = cbase[c + 1];
  const int nv = e1 - e0;
  if (tid < CH) hist[tid] = 0;
  __syncthreads();
  for (int i = tid; i < nv; i += 256) atomicAdd(&hist[erec[e0 + i].y & (CH - 1)], 1);
  __syncthreads();
  int v = (tid < CH) ? hist[tid] : 0;
  sc[tid] = v;
  __syncthreads();
  for (int off = 1; off < 256; off <<= 1) {
    int val = (tid >= off) ? sc[tid - off] : 0;
    __syncthreads();
    sc[tid] += val;
    __syncthreads();
  }
  int excl = sc[tid] - v;  // exclusive scan for tid < CH
  if (tid < CH) lrun[tid] = excl;
  int node = c * CH + tid;
  if (tid < CH && node < NN) {
    rowptr[node] = e0 + excl;
    dinv[node] = rsqrtf((float)(v + 1));  // in-degree + self loop
  }
  if (c == NCHUNK - 1 && tid == CH - 1) rowptr[NN] = NE;
  if (c < NCHUNK - 1 && tid == 0) { /* rowptr[(c+1)*CH] written by next block */ }
  __syncthreads();
  for (int i = tid; i < nv; i += 256) {
    int2 r = erec[e0 + i];
    int pos = atomicAdd(&lrun[r.y & (CH - 1)], 1);
    esrc[e0 + pos] = r.x;
  }
}

// ---------------- W1 pre-swizzle into MFMA B-fragment layout ----------------

__global__ void k_prepB(const float* __restrict__ W, unsigned short* __restrict__ Bp,
                        int Ncol) {
  int idx = blockIdx.x * 256 + threadIdx.x;
  int total = 128 * Ncol;
  if (idx >= total) return;
  int NCH = Ncol >> 4;
  int j = idx & 7;
  int l = (idx >> 3) & 63;
  int rest = idx >> 9;
  int nc = rest % NCH;
  int kc = rest / NCH;
  int k = kc * 32 + (l >> 4) * 8 + j;
  int nn = nc * 16 + (l & 15);
  Bp[idx] = f2bf(W[k * Ncol + nn]);
}

// ---------------- MFMA GEMM1: xw1[M,128] = x[M,128] @ W1, bf16 out ----------------

__global__ __launch_bounds__(256) void k_gemm_mfma(const float* __restrict__ A,
                                                   const unsigned short* __restrict__ Bp,
                                                   unsigned short* __restrict__ C) {
  constexpr int K = 128;
  constexpr int N = KF;
  constexpr int NCH = N / 16;
  const int wv = blockIdx.x * 4 + (threadIdx.x >> 6);
  const int row0 = wv * 16;
  if (row0 >= NN) return;  // 100000 % 16 == 0
  const int lane = threadIdx.x & 63;
  const int m = lane & 15;
  const int q = lane >> 4;

  floatx4 acc[NCH];
#pragma unroll
  for (int i = 0; i < NCH; ++i) acc[i] = (floatx4){0.f, 0.f, 0.f, 0.f};

  const int arow = row0 + m;
#pragma unroll
  for (int kc = 0; kc < 4; ++kc) {
    const float* ap = A + (size_t)arow * K + kc * 32 + q * 8;
    float4 f0 = *(const float4*)ap;
    float4 f1 = *(const float4*)(ap + 4);
    short8 af;
    af[0] = (short)f2bf(f0.x); af[1] = (short)f2bf(f0.y);
    af[2] = (short)f2bf(f0.z); af[3] = (short)f2bf(f0.w);
    af[4] = (short)f2bf(f1.x); af[5] = (short)f2bf(f1.y);
    af[6] = (short)f2bf(f1.z); af[7] = (short)f2bf(f1.w);
    const unsigned short* bp = Bp + (size_t)kc * NCH * 512;
#pragma unroll
    for (int nc = 0; nc < NCH; ++nc) {
      short8 bfr = *(const short8*)(bp + (size_t)nc * 512 + lane * 8);
      acc[nc] = __builtin_amdgcn_mfma_f32_16x16x32_bf16(af, bfr, acc[nc], 0, 0, 0);
    }
  }

#pragma unroll
  for (int nc = 0; nc < NCH; ++nc) {
#pragma unroll
    for (int r = 0; r < 4; ++r) {
      int row = row0 + q * 4 + r;
      C[(size_t)row * N + nc * 16 + m] = f2bf(acc[nc][r]);
    }
  }
}

// ---------------- aggregation, F=128: one wave per node, 8-edge unrolled ----------------

template <bool RELU, bool BIAS>
__global__ __launch_bounds__(128) void k_agg(const unsigned* __restrict__ p,
                                             const float* __restrict__ bias,
                                             const int* __restrict__ rowptr,
                                             const int* __restrict__ esrc,
                                             const float* __restrict__ dinv,
                                             unsigned* __restrict__ out) {
  const int n = blockIdx.x * 2 + (threadIdx.x >> 6);
  const int t = threadIdx.x & 63;

  const float dn = dinv[n];
  const float dn2 = dn * dn;
  float2 f = bf2f(p[(size_t)n * 64 + t]);
  float ax = f.x * dn2, ay = f.y * dn2;

  const int r0 = rowptr[n];
  const int r1 = rowptr[n + 1];
  int i = r0;
  for (; i + 8 <= r1; i += 8) {
    int s0 = esrc[i], s1 = esrc[i + 1], s2 = esrc[i + 2], s3 = esrc[i + 3];
    int s4 = esrc[i + 4], s5 = esrc[i + 5], s6 = esrc[i + 6], s7 = esrc[i + 7];
    float c0 = dinv[s0] * dn, c1 = dinv[s1] * dn, c2 = dinv[s2] * dn, c3 = dinv[s3] * dn;
    float c4 = dinv[s4] * dn, c5 = dinv[s5] * dn, c6 = dinv[s6] * dn, c7 = dinv[s7] * dn;
    unsigned u0 = p[(size_t)s0 * 64 + t];
    unsigned u1 = p[(size_t)s1 * 64 + t];
    unsigned u2 = p[(size_t)s2 * 64 + t];
    unsigned u3 = p[(size_t)s3 * 64 + t];
    unsigned u4 = p[(size_t)s4 * 64 + t];
    unsigned u5 = p[(size_t)s5 * 64 + t];
    unsigned u6 = p[(size_t)s6 * 64 + t];
    unsigned u7 = p[(size_t)s7 * 64 + t];
    f = bf2f(u0); ax = fmaf(c0, f.x, ax); ay = fmaf(c0, f.y, ay);
    f = bf2f(u1); ax = fmaf(c1, f.x, ax); ay = fmaf(c1, f.y, ay);
    f = bf2f(u2); ax = fmaf(c2, f.x, ax); ay = fmaf(c2, f.y, ay);
    f = bf2f(u3); ax = fmaf(c3, f.x, ax); ay = fmaf(c3, f.y, ay);
    f = bf2f(u4); ax = fmaf(c4, f.x, ax); ay = fmaf(c4, f.y, ay);
    f = bf2f(u5); ax = fmaf(c5, f.x, ax); ay = fmaf(c5, f.y, ay);
    f = bf2f(u6); ax = fmaf(c6, f.x, ax); ay = fmaf(c6, f.y, ay);
    f = bf2f(u7); ax = fmaf(c7, f.x, ax); ay = fmaf(c7, f.y, ay);
  }
  for (; i + 4 <= r1; i += 4) {
    int s0 = esrc[i], s1 = esrc[i + 1], s2 = esrc[i + 2], s3 = esrc[i + 3];
    float c0 = dinv[s0] * dn, c1 = dinv[s1] * dn, c2 = dinv[s2] * dn, c3 = dinv[s3] * dn;
    unsigned u0 = p[(size_t)s0 * 64 + t];
    unsigned u1 = p[(size_t)s1 * 64 + t];
    unsigned u2 = p[(size_t)s2 * 64 + t];
    unsigned u3 = p[(size_t)s3 * 64 + t];
    f = bf2f(u0); ax = fmaf(c0, f.x, ax); ay = fmaf(c0, f.y, ay);
    f = bf2f(u1); ax = fmaf(c1, f.x, ax); ay = fmaf(c1, f.y, ay);
    f = bf2f(u2); ax = fmaf(c2, f.x, ax); ay = fmaf(c2, f.y, ay);
    f = bf2f(u3); ax = fmaf(c3, f.x, ax); ay = fmaf(c3, f.y, ay);
  }
  for (; i < r1; ++i) {
    int s = esrc[i];
    float c = dinv[s] * dn;
    f = bf2f(p[(size_t)s * 64 + t]);
    ax = fmaf(c, f.x, ax); ay = fmaf(c, f.y, ay);
  }

  if (BIAS) {
    float2 bb = ((const float2*)bias)[t];
    ax += bb.x; ay += bb.y;
  }
  if (RELU) { ax = fmaxf(ax, 0.f); ay = fmaxf(ay, 0.f); }
  out[(size_t)n * 64 + t] = (unsigned)f2bf(ax) | ((unsigned)f2bf(ay) << 16);
}

// ---------------- mean pool over sorted batch (F=128, bf16 in, f32 out) ----------------

__global__ __launch_bounds__(256) void k_pool(const unsigned* __restrict__ p,
                                              const int* __restrict__ batch,
                                              float* __restrict__ pooled_raw) {
  int g = blockIdx.x;
  int t = threadIdx.x & 63;   // feature uint (2 bf16)
  int wv = threadIdx.x >> 6;  // 4 waves split the node range
  int lo = 0, hi = NN;
  while (lo < hi) { int mid = (lo + hi) >> 1; if (batch[mid] < g) lo = mid + 1; else hi = mid; }
  int start = lo;
  hi = NN;
  while (lo < hi) { int mid = (lo + hi) >> 1; if (batch[mid] < g + 1) lo = mid + 1; else hi = mid; }
  int end = lo;

  float sx = 0.f, sy = 0.f;
  int n = start + wv;
  for (; n + 12 < end; n += 16) {
    unsigned u0 = p[(size_t)n * 64 + t];
    unsigned u1 = p[(size_t)(n + 4) * 64 + t];
    unsigned u2 = p[(size_t)(n + 8) * 64 + t];
    unsigned u3 = p[(size_t)(n + 12) * 64 + t];
    float2 f0 = bf2f(u0), f1 = bf2f(u1), f2 = bf2f(u2), f3 = bf2f(u3);
    sx += (f0.x + f1.x) + (f2.x + f3.x);
    sy += (f0.y + f1.y) + (f2.y + f3.y);
  }
  for (; n < end; n += 4) {
    float2 f = bf2f(p[(size_t)n * 64 + t]);
    sx += f.x; sy += f.y;
  }

  __shared__ float sh[4][128];
  sh[wv][2 * t] = sx;
  sh[wv][2 * t + 1] = sy;
  __syncthreads();
  if (wv == 0) {
    float vx = sh[0][2 * t] + sh[1][2 * t] + sh[2][2 * t] + sh[3][2 * t];
    float vy = sh[0][2 * t + 1] + sh[1][2 * t + 1] + sh[2][2 * t + 1] + sh[3][2 * t + 1];
    float c = fmaxf((float)(end - start), 1.f);
    pooled_raw[g * KF + 2 * t] = vx / c;
    pooled_raw[g * KF + 2 * t + 1] = vy / c;
  }
}

// ---------------- fused mini-GEMM (pooled = praw @ W2 + b2) + heads ----------------

__global__ __launch_bounds__(256) void k_heads(const float* __restrict__ praw,
                                               const float* __restrict__ W2,
                                               const float* __restrict__ b2,
                                               const float* __restrict__ Wg,
                                               const float* __restrict__ bg,
                                               const float* __restrict__ Wf,
                                               const float* __restrict__ bfb,
                                               float* __restrict__ out) {
  int b = blockIdx.x;
  int t = threadIdx.x;  // 256
  __shared__ float pr[KF];
  __shared__ float p[H2F];
  if (t < KF) pr[t] = praw[b * KF + t];
  __syncthreads();
  float acc = b2[t];
#pragma unroll 8
  for (int d = 0; d < KF; ++d) acc = fmaf(pr[d], W2[d * H2F + t], acc);
  p[t] = acc;
  __syncthreads();
  if (t < NGRP) {
    float a = bg[t];
    for (int d = 0; d < H2F; ++d) a = fmaf(p[d], Wg[d * NGRP + t], a);
    out[b * NGRP + t] = a;
  } else if (t >= 64 && t < 64 + NGRP * NFAM) {
    int u = t - 64;
    int g = u / NFAM;
    int ff = u % NFAM;
    float a = bfb[g * NFAM + ff];
    for (int d = 0; d < H2F; ++d) a = fmaf(p[d], Wf[(g * H2F + d) * NFAM + ff], a);
    out[NGR * NGRP + (size_t)g * NGR * NFAM + b * NFAM + ff] = a;
  }
}

// ---------------- launch ----------------

extern "C" void kernel_launch(void* const* d_in, const int* in_sizes, int n_in,
                              void* d_out, int out_size, void* d_ws, size_t ws_size,
                              hipStream_t stream) {
  const float* x    = (const float*)d_in[0];
  const int*   ei   = (const int*)d_in[1];
  const int*   batch= (const int*)d_in[2];
  const float* W1   = (const float*)d_in[3];
  const float* b1   = (const float*)d_in[4];
  const float* W2   = (const float*)d_in[5];
  const float* b2   = (const float*)d_in[6];
  const float* Wg   = (const float*)d_in[7];
  const float* bg   = (const float*)d_in[8];
  const float* Wf   = (const float*)d_in[9];
  const float* bfb  = (const float*)d_in[10];
  float* out = (float*)d_out;

  char* w = (char*)d_ws;
  auto take = [&](size_t bytes) {
    char* p = w;
    w += (bytes + 255) & ~(size_t)255;
    return (void*)p;
  };
  int*   mat   = (int*)take((size_t)NT * NCHUNK * 4);
  int*   tot   = (int*)take((size_t)NCHUNK * 4);
  int*   cbase = (int*)take((size_t)(NCHUNK + 1) * 4);
  int2*  erec  = (int2*)take((size_t)NT * PT * 8);
  int*   esrc  = (int*)take((size_t)NE * 4);
  int*   rowptr= (int*)take((size_t)(NN + 1) * 4);
  float* dinv  = (float*)take((size_t)NN * 4);
  float* praw  = (float*)take((size_t)NGR * KF * 4);
  unsigned short* Bp1 = (unsigned short*)take((size_t)KF * KF * 2);
  unsigned* xw1 = (unsigned*)take((size_t)NN * KF * 2);
  unsigned* h1  = (unsigned*)take((size_t)NN * KF * 2);
  unsigned* agg2= (unsigned*)take((size_t)NN * KF * 2);

  k_phist<<<NT, 256, 0, stream>>>(ei, mat);
  k_colsum<<<(NCHUNK + 3) / 4, 256, 0, stream>>>(mat, tot);
  k_scantot<<<1, 256, 0, stream>>>(tot, cbase);
  k_colfix<<<(NCHUNK + 3) / 4, 256, 0, stream>>>(mat, cbase);
  k_pscatter<<<NT, 256, 0, stream>>>(ei, mat, erec);
  k_sort<<<NCHUNK, 256, 0, stream>>>(erec, cbase, esrc, rowptr, dinv);

  k_prepB<<<(KF * KF + 255) / 256, 256, 0, stream>>>(W1, Bp1, KF);
  k_gemm_mfma<<<1563, 256, 0, stream>>>(x, Bp1, (unsigned short*)xw1);

  k_agg<true, true><<<NN / 2, 128, 0, stream>>>(xw1, b1, rowptr, esrc, dinv, h1);
  k_agg<false, false><<<NN / 2, 128, 0, stream>>>(h1, nullptr, rowptr, esrc, dinv, agg2);

  k_pool<<<NGR, 256, 0, stream>>>(agg2, batch, praw);
  k_heads<<<NGR, 256, 0, stream>>>(praw, W2, b2, Wg, bg, Wf, bfb, out);
}